// Round 2
// baseline (182.434 us; speedup 1.0000x reference)
//
#include <hip/hip_runtime.h>

typedef unsigned int   uint_t;
typedef unsigned short ushort_t;

#define D_DIM    256
#define BM       64
#define NTHREADS 512

typedef __attribute__((ext_vector_type(8))) short bf16x8;
typedef __attribute__((ext_vector_type(4))) float f32x4;

__device__ __forceinline__ ushort_t f2bf(float f) {
    union { float f; uint_t u; } v; v.f = f;
    uint_t u = v.u;
    // round-to-nearest-even bf16
    uint_t r = (u + 0x7fffu + ((u >> 16) & 1u)) >> 16;
    return (ushort_t)r;
}

// ---- W1 fp32 -> bf16 convert (65536 elements, vectorized x4) ----
__global__ void cvt_w1(const float* __restrict__ w, ushort_t* __restrict__ o) {
    int i = blockIdx.x * 256 + threadIdx.x;   // float4 index, 16384 total
    float4 v = ((const float4*)w)[i];
    uint_t lo = (uint_t)f2bf(v.x) | ((uint_t)f2bf(v.y) << 16);
    uint_t hi = (uint_t)f2bf(v.z) | ((uint_t)f2bf(v.w) << 16);
    uint2 p; p.x = lo; p.y = hi;
    ((uint2*)o)[i] = p;
}

// ---- fused LN + Linear(256,256)+SiLU + Linear(256,1) ----
// __launch_bounds__(512,4): 4 waves/EU -> 2 blocks/CU (512 thr = 8 waves = 2/EU
// per block). 2 blocks/CU lets block B's LN HBM loads overlap block A's MFMA.
__global__ __launch_bounds__(NTHREADS, 4)
void fused_critic(const float* __restrict__ feat,
                  const float* __restrict__ gamma,
                  const float* __restrict__ beta,
                  const ushort_t* __restrict__ w1bf,
                  const float* __restrict__ b1,
                  const float* __restrict__ wv,
                  const float* __restrict__ bv,
                  float* __restrict__ out) {
    __shared__ __align__(16) ushort_t xn[BM * D_DIM];  // bf16, XOR-swizzled rows
    __shared__ float rowsum[BM];

    const int tid   = threadIdx.x;
    const int brow0 = blockIdx.x * BM;

    // ================= LayerNorm phase =================
    {
        const int r = tid >> 3;   // 0..63 local row
        const int t = tid & 7;    // 8 threads per row
        const float4* f4 = (const float4*)(feat + (size_t)(brow0 + r) * D_DIM);
        float4 x[8];
        float s = 0.f, s2 = 0.f;
#pragma unroll
        for (int i = 0; i < 8; ++i) {
            const int c = i * 8 + t;          // float4 column index 0..63
            float4 v = f4[c];
            x[i] = v;
            s  += v.x + v.y + v.z + v.w;
            s2 += v.x * v.x + v.y * v.y + v.z * v.z + v.w * v.w;
        }
        // reduce over the 8 threads of this row (lane bits 0..2)
        s  += __shfl_xor(s, 1);  s2 += __shfl_xor(s2, 1);
        s  += __shfl_xor(s, 2);  s2 += __shfl_xor(s2, 2);
        s  += __shfl_xor(s, 4);  s2 += __shfl_xor(s2, 4);
        const float mean = s * (1.f / 256.f);
        const float var  = s2 * (1.f / 256.f) - mean * mean;
        const float rstd = rsqrtf(var + 1e-5f);

        if (tid < BM) rowsum[tid] = 0.f;

        const float4* g4  = (const float4*)gamma;
        const float4* be4 = (const float4*)beta;
        const uint_t swz = (uint_t)((r & 7) << 4);
#pragma unroll
        for (int i = 0; i < 8; ++i) {
            const int c = i * 8 + t;
            float4 g = g4[c], bb = be4[c];
            float4 v = x[i];
            uint_t lo = (uint_t)f2bf((v.x - mean) * rstd * g.x + bb.x)
                      | ((uint_t)f2bf((v.y - mean) * rstd * g.y + bb.y) << 16);
            uint_t hi = (uint_t)f2bf((v.z - mean) * rstd * g.z + bb.z)
                      | ((uint_t)f2bf((v.w - mean) * rstd * g.w + bb.w) << 16);
            uint_t off = ((uint_t)(r * 512 + c * 8)) ^ swz;  // byte offset
            uint2 p; p.x = lo; p.y = hi;
            *(uint2*)((char*)xn + off) = p;
        }
    }
    __syncthreads();

    // ================= GEMM phase (bf16 MFMA 16x16x32) =================
    const int w   = tid >> 6;  // wave 0..7
    const int l   = tid & 63;
    const int wm  = w >> 2;    // 0..1 : 32-row slice
    const int wn  = w & 3;     // 0..3 : 64-col slice
    const int l15 = l & 15;
    const int lg  = l >> 4;    // 0..3

    f32x4 acc[2][4] = {};

    const uint_t swz = (uint_t)((l15 & 7) << 4);
    uint_t abase[2];
#pragma unroll
    for (int m = 0; m < 2; ++m)
        abase[m] = (uint_t)((wm * 32 + m * 16 + l15) * 512 + lg * 16);

    // B fragment: col = wn*64 + n*16 + l15 (W1 row), k = kt*32 + lg*8
    const ushort_t* bbase = w1bf + (size_t)(wn * 64 + l15) * D_DIM + lg * 8;

#pragma unroll
    for (int kt = 0; kt < 8; ++kt) {
        bf16x8 aF[2], bF[4];
#pragma unroll
        for (int m = 0; m < 2; ++m)
            aF[m] = __builtin_bit_cast(bf16x8,
                *(const uint4*)((const char*)xn + ((abase[m] + kt * 64) ^ swz)));
#pragma unroll
        for (int n = 0; n < 4; ++n)
            bF[n] = __builtin_bit_cast(bf16x8,
                *(const uint4*)(bbase + n * 16 * D_DIM + kt * 32));
#pragma unroll
        for (int m = 0; m < 2; ++m)
#pragma unroll
            for (int n = 0; n < 4; ++n)
                acc[m][n] = __builtin_amdgcn_mfma_f32_16x16x32_bf16(aF[m], bF[n], acc[m][n], 0, 0, 0);
    }

    // ================= epilogue: bias + SiLU + dot(Wv) =================
    float b1v[4], wvv[4];
#pragma unroll
    for (int n = 0; n < 4; ++n) {
        int col = wn * 64 + n * 16 + l15;
        b1v[n] = b1[col];
        wvv[n] = wv[col];
    }
#pragma unroll
    for (int m = 0; m < 2; ++m) {
#pragma unroll
        for (int rg = 0; rg < 4; ++rg) {
            float s = 0.f;
#pragma unroll
            for (int n = 0; n < 4; ++n) {
                float h = acc[m][n][rg] + b1v[n];
                float sig = 1.f / (1.f + __expf(-h));
                s += h * sig * wvv[n];
            }
            // reduce across the 16 column-lanes (C/D: col = lane&15)
            s += __shfl_xor(s, 1);
            s += __shfl_xor(s, 2);
            s += __shfl_xor(s, 4);
            s += __shfl_xor(s, 8);
            if (l15 == 0) {
                int row = wm * 32 + m * 16 + lg * 4 + rg;  // C/D: row=(lane>>4)*4+reg
                atomicAdd(&rowsum[row], s);
            }
        }
    }
    __syncthreads();
    if (tid < BM) out[brow0 + tid] = rowsum[tid] + bv[0];
}

extern "C" void kernel_launch(void* const* d_in, const int* in_sizes, int n_in,
                              void* d_out, int out_size, void* d_ws, size_t ws_size,
                              hipStream_t stream) {
    const float* feat  = (const float*)d_in[0];
    const float* gamma = (const float*)d_in[1];
    const float* beta  = (const float*)d_in[2];
    const float* W1    = (const float*)d_in[3];
    const float* b1    = (const float*)d_in[4];
    const float* wv    = (const float*)d_in[5];
    const float* bv    = (const float*)d_in[6];
    float* out = (float*)d_out;

    ushort_t* w1bf = (ushort_t*)d_ws;  // 128 KB, L2-resident

    hipLaunchKernelGGL(cvt_w1, dim3(64), dim3(256), 0, stream, W1, w1bf);

    const int nblocks = out_size / BM;  // 262144/64 = 4096
    hipLaunchKernelGGL(fused_critic, dim3(nblocks), dim3(NTHREADS), 0, stream,
                       feat, gamma, beta, w1bf, b1, wv, bv, out);
}